// Round 2
// baseline (3945.090 us; speedup 1.0000x reference)
//
#include <hip/hip_runtime.h>

#define B_ 128
#define T_ 256
#define L_ 4
#define DC_ 128
#define DW_ 128
#define H_ 256
#define V_ 6000
#define Z4_ 1024   // 4*H
#define KR_ 384    // DW+H

__device__ __forceinline__ float sigm(float x) { return 1.0f / (1.0f + expf(-x)); }

// ------------------------------------------------------------------
// Kernel 1: vocab composition table (hoisted out of the scan).
// Vtab[v][w][e] = tanh( (sigmoid(emb_v @ reset_W[w] + reset_b[w]) * emb_v) @ com_W + com_b )[e]
// One block per vocab id; the 4 window sizes run as 4 thread groups.
// ------------------------------------------------------------------
__global__ __launch_bounds__(512) void vtab_kernel(
    const float* __restrict__ char_emb, const float* __restrict__ reset_W,
    const float* __restrict__ reset_b, const float* __restrict__ com_W,
    const float* __restrict__ com_b, float* __restrict__ Vtab)
{
  const int v = blockIdx.x;          // 0..5999
  const int tid = threadIdx.x;
  const int w = tid >> 7;            // 0..3
  const int e = tid & 127;           // 0..127
  __shared__ float emb[DC_];
  __shared__ float ge[L_][DC_];
  if (tid < DC_) emb[tid] = char_emb[v * DC_ + tid];
  __syncthreads();
  float acc = reset_b[w * DC_ + e];
  const float* W = reset_W + (size_t)w * DC_ * DC_;
  #pragma unroll 8
  for (int k = 0; k < DC_; ++k) acc = fmaf(emb[k], W[k * DC_ + e], acc);
  ge[w][e] = sigm(acc) * emb[e];
  __syncthreads();
  float acc2 = com_b[e];
  #pragma unroll 8
  for (int k = 0; k < DC_; ++k) acc2 = fmaf(ge[w][k], com_W[k * DW_ + e], acc2);
  Vtab[((size_t)v * L_ + w) * DW_ + e] = tanhf(acc2);
}

// z[tid] = bias[tid] + sum_k xh[k] * K[k][tid]   (K is 384 x 1024 f32 row-major)
__device__ __forceinline__ void lstm_matvec(const float* __restrict__ K,
                                            const float* __restrict__ xh,
                                            const float* __restrict__ biasL,
                                            float* __restrict__ zbuf, int tid)
{
  float a = biasL[tid];
  const float* Kp = K + tid;
  const float4* x4p = (const float4*)xh;
  #pragma unroll 4
  for (int k4 = 0; k4 < KR_ / 4; ++k4) {
    float4 x4 = x4p[k4];
    size_t base = (size_t)(4 * k4) * Z4_;
    a = fmaf(x4.x, Kp[base], a);
    a = fmaf(x4.y, Kp[base + Z4_], a);
    a = fmaf(x4.z, Kp[base + 2 * Z4_], a);
    a = fmaf(x4.w, Kp[base + 3 * Z4_], a);
  }
  zbuf[tid] = a;
}

// ------------------------------------------------------------------
// Kernel 2: sequential scan. One block per batch row; 1024 threads.
// Recurrent state in LDS; weights stream from L2 each step.
// ------------------------------------------------------------------
__global__ __launch_bounds__(1024) void seq_kernel(
    const int* __restrict__ chars, const float* __restrict__ Vtab,
    const float* __restrict__ Kmat, const float* __restrict__ lstm_bias,
    const float* __restrict__ pred_W, const float* __restrict__ pred_b,
    const float* __restrict__ score_U, const float* __restrict__ bos,
    float* __restrict__ out)
{
  const int b = blockIdx.x;
  const int tid = threadIdx.x;

  __shared__ float biasL[Z4_];            // 4 KB
  __shared__ float UL[DW_];
  __shared__ float pbL[DW_];
  __shared__ float ringVt[4][L_ * DW_];   // last 4 chars' composed vecs, 8 KB
  __shared__ float ringP[4][DW_];
  __shared__ float ringH[4][H_];
  __shared__ float ringC[4][H_];
  __shared__ float wordb[L_][DW_];
  __shared__ __align__(16) float xh[KR_];
  __shared__ float zbuf[Z4_];
  __shared__ float pp[8][DW_];            // pred partial sums (8 k-groups of 32)
  __shared__ float scL[4];
  __shared__ int bestwL;

  biasL[tid] = lstm_bias[tid];
  if (tid < DW_) { UL[tid] = score_U[tid]; pbL[tid] = pred_b[tid]; }
  for (int i = tid; i < 4 * L_ * DW_; i += 1024) (&ringVt[0][0])[i] = 0.0f;
  if (tid < DW_) xh[tid] = bos[tid];
  else if (tid < KR_) xh[tid] = 0.0f;
  __syncthreads();

  // ---- initial LSTM: x = bos, c0 = h0 = 0 -> (c1, h1), pred0 ----
  lstm_matvec(Kmat, xh, biasL, zbuf, tid);
  __syncthreads();
  if (tid < H_) {
    float zi = zbuf[tid], zj = zbuf[H_ + tid], zo = zbuf[3 * H_ + tid];
    float ncv = sigm(zi) * tanhf(zj);           // c0 == 0 kills the f-gate term
    float nhv = tanhf(ncv) * sigm(zo);
    #pragma unroll
    for (int s = 0; s < 4; ++s) { ringC[s][tid] = ncv; ringH[s][tid] = nhv; }
  }
  __syncthreads();
  {
    int q = tid >> 7, e = tid & 127;
    float s = 0.0f;
    #pragma unroll 8
    for (int k = q * 32; k < q * 32 + 32; ++k)
      s = fmaf(ringH[0][k], pred_W[k * DW_ + e], s);
    pp[q][e] = s;
  }
  __syncthreads();
  if (tid < DW_) {
    float p = pbL[tid];
    #pragma unroll
    for (int q = 0; q < 8; ++q) p += pp[q][tid];
    p = tanhf(p);
    #pragma unroll
    for (int s = 0; s < 4; ++s) ringP[s][tid] = p;
  }
  __syncthreads();

  // ---- scan over T steps ----
  for (int t = 0; t < T_; ++t) {
    const int slot = t & 3;
    if (tid < L_ * DW_) {
      const int ch = chars[b * T_ + t];
      ringVt[slot][tid] = Vtab[(size_t)ch * (L_ * DW_) + tid];
    }
    __syncthreads();
    if (tid < L_ * DW_) {   // word[w][e] = mean_{c<=w} proj(char_{t-c}, w)[e]
      int w = tid >> 7, e = tid & 127;
      float s = 0.0f;
      #pragma unroll
      for (int c = 0; c < 4; ++c)
        if (c <= w) s += ringVt[(t - c) & 3][w * DW_ + e];
      float il = (w == 0) ? 1.0f : (w == 1) ? 0.5f : (w == 2) ? (1.0f / 3.0f) : 0.25f;
      wordb[w][e] = s * il;
    }
    __syncthreads();
    {   // score[w] = dot(pred_{t-1-w} + U, word[w]); wave w handles score[w]
      int wv = tid >> 6;
      if (wv < 4) {
        int w = wv, l = tid & 63;
        int ps = (t - 1 - w) & 3;
        float p = (ringP[ps][l] + UL[l]) * wordb[w][l]
                + (ringP[ps][l + 64] + UL[l + 64]) * wordb[w][l + 64];
        #pragma unroll
        for (int off = 32; off > 0; off >>= 1) p += __shfl_down(p, off);
        if (l == 0) scL[w] = (w <= t) ? p : -1e30f;
      }
    }
    __syncthreads();
    if (tid == 0) {   // argmax, first max wins (jnp.argmax semantics)
      float bs = scL[0]; int bw = 0;
      #pragma unroll
      for (int w = 1; w < 4; ++w) if (scL[w] > bs) { bs = scL[w]; bw = w; }
      bestwL = bw;
      out[b * T_ + t] = bs;                          // scores (B,T) f32
      out[B_ * T_ + b * T_ + t] = (float)(bw + 1);   // wl (B,T) as f32
    }
    __syncthreads();
    const int bw = bestwL;
    const int hs = (t - 1 - bw) & 3;
    if (tid < DW_) xh[tid] = wordb[bw][tid];
    else if (tid < KR_) xh[tid] = ringH[hs][tid - DW_];
    __syncthreads();
    lstm_matvec(Kmat, xh, biasL, zbuf, tid);
    __syncthreads();
    if (tid < H_) {
      float cprev = ringC[hs][tid];
      float zi = zbuf[tid], zj = zbuf[H_ + tid], zf = zbuf[2 * H_ + tid], zo = zbuf[3 * H_ + tid];
      float ncv = cprev * sigm(zf) + sigm(zi) * tanhf(zj);
      float nhv = tanhf(ncv) * sigm(zo);
      ringC[slot][tid] = ncv;
      ringH[slot][tid] = nhv;
    }
    __syncthreads();
    {   // npred = tanh(nh @ pred_W + pred_b); 8 partial-k groups then reduce
      int q = tid >> 7, e = tid & 127;
      float s = 0.0f;
      #pragma unroll 8
      for (int k = q * 32; k < q * 32 + 32; ++k)
        s = fmaf(ringH[slot][k], pred_W[k * DW_ + e], s);
      pp[q][e] = s;
    }
    __syncthreads();
    if (tid < DW_) {
      float p = pbL[tid];
      #pragma unroll
      for (int q = 0; q < 8; ++q) p += pp[q][tid];
      ringP[slot][tid] = tanhf(p);
    }
    __syncthreads();
  }
}

extern "C" void kernel_launch(void* const* d_in, const int* in_sizes, int n_in,
                              void* d_out, int out_size, void* d_ws, size_t ws_size,
                              hipStream_t stream) {
  const int*   chars     = (const int*)d_in[0];
  const float* char_emb  = (const float*)d_in[1];
  const float* reset_W   = (const float*)d_in[2];
  const float* reset_b   = (const float*)d_in[3];
  const float* com_W     = (const float*)d_in[4];
  const float* com_b     = (const float*)d_in[5];
  const float* lstm_k    = (const float*)d_in[6];
  const float* lstm_bias = (const float*)d_in[7];
  const float* pred_W    = (const float*)d_in[8];
  const float* pred_b    = (const float*)d_in[9];
  const float* score_U   = (const float*)d_in[10];
  const float* bos       = (const float*)d_in[11];

  float* Vtab = (float*)d_ws;   // V*L*DW f32 = 12.3 MB

  vtab_kernel<<<V_, 512, 0, stream>>>(char_emb, reset_W, reset_b, com_W, com_b, Vtab);
  seq_kernel<<<B_, 1024, 0, stream>>>(chars, Vtab, lstm_k, lstm_bias, pred_W,
                                      pred_b, score_U, bos, (float*)d_out);
}

// Round 3
// 2956.032 us; speedup vs baseline: 1.3346x; 1.3346x over previous
//
#include <hip/hip_runtime.h>

#define B_ 128
#define T_ 256
#define L_ 4
#define DC_ 128
#define DW_ 128
#define H_ 256
#define V_ 6000
#define Z4_ 1024   // 4*H
#define KR_ 384    // DW+H
#define S_ 4       // blocks per group (h-split)
#define R_ 2       // batch rows per group
#define G_ 64      // groups = B/R
#define HC_ 64     // h-chunk per block = H/S

// d_ws layout (bytes)
#define WS_FLAGS 0                         // 256 u32
#define WS_VTAB  4096                      // V*L*DW f32 = 12,288,000
#define WS_NH    (WS_VTAB + V_*L_*DW_*4)   // [2][G][S][R][HC] f32 = 256 KB
#define WS_PP    (WS_NH + 2*G_*S_*R_*HC_*4)// [2][G][S][R][DW] f32 = 512 KB

__device__ __forceinline__ float sigm(float x) { return 1.0f / (1.0f + expf(-x)); }

__device__ __forceinline__ void st_a(float* p, float v) {
  __hip_atomic_store(p, v, __ATOMIC_RELAXED, __HIP_MEMORY_SCOPE_AGENT);
}
__device__ __forceinline__ float ld_a(const float* p) {
  return __hip_atomic_load(p, __ATOMIC_RELAXED, __HIP_MEMORY_SCOPE_AGENT);
}

// ------------------------------------------------------------------
// Kernel 1: vocab composition table (unchanged from round 2 — passed).
// ------------------------------------------------------------------
__global__ __launch_bounds__(512) void vtab_kernel(
    const float* __restrict__ char_emb, const float* __restrict__ reset_W,
    const float* __restrict__ reset_b, const float* __restrict__ com_W,
    const float* __restrict__ com_b, float* __restrict__ Vtab)
{
  const int v = blockIdx.x;
  const int tid = threadIdx.x;
  const int w = tid >> 7;
  const int e = tid & 127;
  __shared__ float emb[DC_];
  __shared__ float ge[L_][DC_];
  if (tid < DC_) emb[tid] = char_emb[v * DC_ + tid];
  __syncthreads();
  float acc = reset_b[w * DC_ + e];
  const float* W = reset_W + (size_t)w * DC_ * DC_;
  #pragma unroll 8
  for (int k = 0; k < DC_; ++k) acc = fmaf(emb[k], W[k * DC_ + e], acc);
  ge[w][e] = sigm(acc) * emb[e];
  __syncthreads();
  float acc2 = com_b[e];
  #pragma unroll 8
  for (int k = 0; k < DC_; ++k) acc2 = fmaf(ge[w][k], com_W[k * DW_ + e], acc2);
  Vtab[((size_t)v * L_ + w) * DW_ + e] = tanhf(acc2);
}

// ------------------------------------------------------------------
// Kernel 2: distributed sequential scan.
// 256 blocks x 1024 threads. Block (s,g): s = blk>>6 owns h-chunk
// [s*64, s*64+64) of rows {2g, 2g+1}. Weights streamed once per group
// member (W/4 per CU) and shared across R=2 rows -> per-CU L2 traffic
// drops 4x vs round 2. One mailbox exchange + flag wait per step.
// ------------------------------------------------------------------
__global__ __launch_bounds__(1024, 4) void seq_kernel(
    const int* __restrict__ chars, const float* __restrict__ Vtab,
    const float* __restrict__ Kmat, const float* __restrict__ lstm_bias,
    const float* __restrict__ pred_W, const float* __restrict__ pred_b,
    const float* __restrict__ score_U, const float* __restrict__ bos,
    float* __restrict__ out, unsigned int* __restrict__ flags,
    float* __restrict__ nh_mb, float* __restrict__ pp_mb)
{
  const int blk = blockIdx.x;
  const int s = blk >> 6;     // 0..3  (h-split index)
  const int g = blk & 63;     // group = pair of batch rows
  const int tid = threadIdx.x;

  __shared__ __align__(16) float2 xh2[KR_];   // {row0,row1} interleaved
  __shared__ float biasC[4 * HC_];            // bias for my 256 z-cols, gate-major
  __shared__ float UL[DW_], pbL[DW_];
  __shared__ int   charsL[R_][T_];
  __shared__ float ringVt[R_][4][L_ * DW_];   // 16 KB
  __shared__ float hring[4][R_][H_];          // 8 KB (full h, replicated)
  __shared__ float cring[4][R_][HC_];         // local chunk only
  __shared__ float pring[4][R_][DW_];         // replicated
  __shared__ float wordb[R_][L_][DW_];
  __shared__ float2 zpart[4][256];            // kq x col -> 8 KB
  __shared__ float zc[R_][4][HC_];            // z by [row][gate][hloc]
  __shared__ float2 ppart[8][DW_];            // 8 KB
  __shared__ float2 nhl[HC_];                 // new h, local chunk, {r0,r1}
  __shared__ float scL[R_][L_];
  __shared__ int bwL[R_];

  // ---- one-time loads ----
  if (tid < 4 * HC_) biasC[tid] = lstm_bias[(tid >> 6) * H_ + s * HC_ + (tid & 63)];
  if (tid < DW_) { UL[tid] = score_U[tid]; pbL[tid] = pred_b[tid]; }
  for (int i = tid; i < R_ * T_; i += 1024)
    charsL[i >> 8][i & 255] = chars[(2 * g + (i >> 8)) * T_ + (i & 255)];
  for (int i = tid; i < R_ * 4 * L_ * DW_; i += 1024) ((float*)ringVt)[i] = 0.0f;
  __syncthreads();

  // phase p = t+1 (p=0 is the bos-init step). flags are monotonic step counters.
  for (int t = -1; t < T_; ++t) {
    const int slot = (t < 0) ? 0 : (t & 3);
    const int p = t + 1;
    const int par = p & 1;

    if (t >= 0) {
      { // Vtab gather for char t (both rows)
        int r = tid >> 9, idx = tid & 511;
        int ch = charsL[r][t];
        ringVt[r][slot][idx] = Vtab[(size_t)ch * (L_ * DW_) + idx];
      }
      __syncthreads();
      { // word[r][w][e] = mean_{c<=w} ringVt
        int r = tid >> 9, rem = tid & 511, w = rem >> 7, e = rem & 127;
        float sacc = 0.0f;
        #pragma unroll
        for (int c = 0; c < L_; ++c)
          if (c <= w) sacc += ringVt[r][(t - c) & 3][w * DW_ + e];
        const float il = (w == 0) ? 1.0f : (w == 1) ? 0.5f : (w == 2) ? (1.0f / 3.0f) : 0.25f;
        wordb[r][w][e] = sacc * il;
      }
      __syncthreads();
      { // scores: 8 waves, one per (r,w)
        int wv = tid >> 6;
        if (wv < 8) {
          int r = wv >> 2, w = wv & 3, l = tid & 63;
          int ps = (t - 1 - w) & 3;
          float pv = (pring[ps][r][l] + UL[l]) * wordb[r][w][l]
                   + (pring[ps][r][l + 64] + UL[l + 64]) * wordb[r][w][l + 64];
          #pragma unroll
          for (int off = 32; off; off >>= 1) pv += __shfl_down(pv, off);
          if (l == 0) scL[r][w] = (w <= t) ? pv : -1e30f;
        }
      }
      __syncthreads();
      if (tid < R_) { // argmax (first max wins), identical in all 4 blocks
        int r = tid;
        float bs = scL[r][0]; int bw = 0;
        #pragma unroll
        for (int w = 1; w < L_; ++w) if (scL[r][w] > bs) { bs = scL[r][w]; bw = w; }
        bwL[r] = bw;
        if (s == 0) {
          int row = 2 * g + r;
          out[row * T_ + t] = bs;
          out[B_ * T_ + row * T_ + t] = (float)(bw + 1);
        }
      }
      __syncthreads();
      if (tid < KR_) { // next LSTM input [word ; h_prev], row-interleaved
        int j = tid; float v0, v1;
        if (j < DW_) { v0 = wordb[0][bwL[0]][j]; v1 = wordb[1][bwL[1]][j]; }
        else {
          int hj = j - DW_;
          v0 = hring[(t - 1 - bwL[0]) & 3][0][hj];
          v1 = hring[(t - 1 - bwL[1]) & 3][1][hj];
        }
        xh2[j] = make_float2(v0, v1);
      }
      __syncthreads();
    } else {
      if (tid < KR_) {
        float v = (tid < DW_) ? bos[tid] : 0.0f;
        xh2[tid] = make_float2(v, v);
      }
      __syncthreads();
    }

    { // z accumulate: tid = kq*256 + gate*64 + hloc ; my 256 z-cols, 2 rows, k-quarter
      int kq = tid >> 8, rem = tid & 255;
      const float* Kp = Kmat + ((rem >> 6) * H_ + s * HC_ + (rem & 63)); // col = gate*256 + s*64 + hloc
      float a0 = 0.0f, a1 = 0.0f;
      int k0 = kq * 96;
      #pragma unroll 8
      for (int k = k0; k < k0 + 96; ++k) {
        float w = Kp[(size_t)k * Z4_];
        float2 x = xh2[k];
        a0 = fmaf(w, x.x, a0);
        a1 = fmaf(w, x.y, a1);
      }
      zpart[kq][rem] = make_float2(a0, a1);
    }
    __syncthreads();
    if (tid < 512) { // reduce k-quarters + bias
      int r = tid >> 8, cc = tid & 255;
      float z = biasC[cc];
      #pragma unroll
      for (int kq = 0; kq < 4; ++kq) z += r ? zpart[kq][cc].y : zpart[kq][cc].x;
      zc[r][cc >> 6][cc & 63] = z;
    }
    __syncthreads();
    if (tid < R_ * HC_) { // gates -> nc, nh (owner only); publish nh
      int r = tid >> 6, h = tid & 63;
      float zi = zc[r][0][h], zj = zc[r][1][h], zf = zc[r][2][h], zo = zc[r][3][h];
      float cprev = (t < 0) ? 0.0f : cring[(t - 1 - bwL[r]) & 3][r][h];
      float nc = cprev * sigm(zf) + sigm(zi) * tanhf(zj);
      float nh = tanhf(nc) * sigm(zo);
      if (t < 0) { for (int q = 0; q < 4; ++q) cring[q][r][h] = nc; }
      else cring[slot][r][h] = nc;
      if (r == 0) nhl[h].x = nh; else nhl[h].y = nh;
      st_a(&nh_mb[(((size_t)par * G_ + g) * S_ + s) * (R_ * HC_) + r * HC_ + h], nh);
    }
    __syncthreads();
    { // pred partial over my 64 h-rows: tid = kq*128 + e (kq 0..7)
      int kq = tid >> 7, e = tid & 127;
      float a0 = 0.0f, a1 = 0.0f;
      int kb = kq * 8;
      #pragma unroll
      for (int kk = 0; kk < 8; ++kk) {
        float w = pred_W[(size_t)(s * HC_ + kb + kk) * DW_ + e];
        float2 nh2 = nhl[kb + kk];
        a0 = fmaf(w, nh2.x, a0);
        a1 = fmaf(w, nh2.y, a1);
      }
      ppart[kq][e] = make_float2(a0, a1);
    }
    __syncthreads();
    if (tid < R_ * DW_) {
      int r = tid >> 7, e = tid & 127;
      float acc = 0.0f;
      #pragma unroll
      for (int kq = 0; kq < 8; ++kq) acc += r ? ppart[kq][e].y : ppart[kq][e].x;
      st_a(&pp_mb[(((size_t)par * G_ + g) * S_ + s) * (R_ * DW_) + r * DW_ + e], acc);
    }
    __syncthreads();  // drains all mailbox stores (vmcnt 0) before flag
    if (tid == 0)
      __hip_atomic_store(&flags[blk], (unsigned)(p + 1), __ATOMIC_RELEASE, __HIP_MEMORY_SCOPE_AGENT);
    if (tid < S_) { // wait for the 3 partners (and self)
      const unsigned target = (unsigned)(p + 1);
      const unsigned int* fp = &flags[tid * G_ + g];
      while (__hip_atomic_load(fp, __ATOMIC_RELAXED, __HIP_MEMORY_SCOPE_AGENT) < target)
        __builtin_amdgcn_s_sleep(2);
    }
    __syncthreads();
    // assemble full nh ring + pred (identical order in all blocks -> bit-identical)
    if (tid < R_ * H_) {
      int r = tid >> 8, hg = tid & 255, sp = hg >> 6, h = hg & 63;
      float v = ld_a(&nh_mb[(((size_t)par * G_ + g) * S_ + sp) * (R_ * HC_) + r * HC_ + h]);
      if (t < 0) { for (int q = 0; q < 4; ++q) hring[q][r][hg] = v; }
      else hring[slot][r][hg] = v;
    } else if (tid < R_ * H_ + R_ * DW_) {
      int q2 = tid - R_ * H_;
      int r = q2 >> 7, e = q2 & 127;
      float acc = pbL[e];
      #pragma unroll
      for (int sp = 0; sp < S_; ++sp)
        acc += ld_a(&pp_mb[(((size_t)par * G_ + g) * S_ + sp) * (R_ * DW_) + r * DW_ + e]);
      float pv = tanhf(acc);
      if (t < 0) { for (int q = 0; q < 4; ++q) pring[q][r][e] = pv; }
      else pring[slot][r][e] = pv;
    }
    __syncthreads();
  }
}

extern "C" void kernel_launch(void* const* d_in, const int* in_sizes, int n_in,
                              void* d_out, int out_size, void* d_ws, size_t ws_size,
                              hipStream_t stream) {
  const int*   chars     = (const int*)d_in[0];
  const float* char_emb  = (const float*)d_in[1];
  const float* reset_W   = (const float*)d_in[2];
  const float* reset_b   = (const float*)d_in[3];
  const float* com_W     = (const float*)d_in[4];
  const float* com_b     = (const float*)d_in[5];
  const float* lstm_k    = (const float*)d_in[6];
  const float* lstm_bias = (const float*)d_in[7];
  const float* pred_W    = (const float*)d_in[8];
  const float* pred_b    = (const float*)d_in[9];
  const float* score_U   = (const float*)d_in[10];
  const float* bos       = (const float*)d_in[11];

  char* ws = (char*)d_ws;
  unsigned int* flags = (unsigned int*)(ws + WS_FLAGS);
  float* Vtab  = (float*)(ws + WS_VTAB);
  float* nh_mb = (float*)(ws + WS_NH);
  float* pp_mb = (float*)(ws + WS_PP);

  // d_ws is re-poisoned to 0xAA before every timed launch: flags MUST be zeroed.
  hipMemsetAsync(flags, 0, 256 * sizeof(unsigned int), stream);
  vtab_kernel<<<V_, 512, 0, stream>>>(char_emb, reset_W, reset_b, com_W, com_b, Vtab);
  seq_kernel<<<256, 1024, 0, stream>>>(chars, Vtab, lstm_k, lstm_bias, pred_W,
                                       pred_b, score_U, bos, (float*)d_out,
                                       flags, nh_mb, pp_mb);
}

// Round 4
// 2937.210 us; speedup vs baseline: 1.3431x; 1.0064x over previous
//
#include <hip/hip_runtime.h>

#define B_ 128
#define T_ 256
#define L_ 4
#define DC_ 128
#define DW_ 128
#define H_ 256
#define V_ 6000
#define Z4_ 1024   // 4*H
#define S_ 8       // blocks per group (z-column split)
#define R_ 4       // batch rows per group
#define G_ 32      // groups = B/R
#define HC_ 32     // h-chunk per block = H/S

// d_ws layout (bytes)
#define WS_FLAGS 0                            // 256 u32 (+pad)
#define WS_VTAB  4096                         // V*L*DW f32 = 12,288,000
#define WS_NH    (WS_VTAB + V_*L_*DW_*4)      // [2][G][S][R][HC] f32 = 256 KB
#define WS_PP    (WS_NH + 2*G_*S_*R_*HC_*4)   // [2][G][S][R][DW] f32 = 1 MB

__device__ __forceinline__ float sigm(float x) { return 1.0f / (1.0f + expf(-x)); }

__device__ __forceinline__ void st_a(float* p, float v) {
  __hip_atomic_store(p, v, __ATOMIC_RELAXED, __HIP_MEMORY_SCOPE_AGENT);
}
__device__ __forceinline__ float ld_a(const float* p) {
  return __hip_atomic_load(p, __ATOMIC_RELAXED, __HIP_MEMORY_SCOPE_AGENT);
}
// first-max-wins argmax over 4 (jnp.argmax tie semantics)
__device__ __forceinline__ int amax4(const float* sc) {
  float bs = sc[0]; int bw = 0;
  if (sc[1] > bs) { bs = sc[1]; bw = 1; }
  if (sc[2] > bs) { bs = sc[2]; bw = 2; }
  if (sc[3] > bs) { bs = sc[3]; bw = 3; }
  return bw;
}

// ------------------------------------------------------------------
// Kernel 1: vocab composition table (unchanged — verified).
// ------------------------------------------------------------------
__global__ __launch_bounds__(512) void vtab_kernel(
    const float* __restrict__ char_emb, const float* __restrict__ reset_W,
    const float* __restrict__ reset_b, const float* __restrict__ com_W,
    const float* __restrict__ com_b, float* __restrict__ Vtab)
{
  const int v = blockIdx.x;
  const int tid = threadIdx.x;
  const int w = tid >> 7;
  const int e = tid & 127;
  __shared__ float emb[DC_];
  __shared__ float ge[L_][DC_];
  if (tid < DC_) emb[tid] = char_emb[v * DC_ + tid];
  __syncthreads();
  float acc = reset_b[w * DC_ + e];
  const float* W = reset_W + (size_t)w * DC_ * DC_;
  #pragma unroll 8
  for (int k = 0; k < DC_; ++k) acc = fmaf(emb[k], W[k * DC_ + e], acc);
  ge[w][e] = sigm(acc) * emb[e];
  __syncthreads();
  float acc2 = com_b[e];
  #pragma unroll 8
  for (int k = 0; k < DC_; ++k) acc2 = fmaf(ge[w][k], com_W[k * DW_ + e], acc2);
  Vtab[((size_t)v * L_ + w) * DW_ + e] = tanhf(acc2);
}

// ------------------------------------------------------------------
// Kernel 2: distributed scan, S=8 x R=4. blk = s*32 + g.
// Critical-path reorder: gather/word/speculative-zx run BEFORE the
// flag wait, hiding the inter-block exchange latency.
// ------------------------------------------------------------------
__global__ __launch_bounds__(1024, 4) void seq_kernel(
    const int* __restrict__ chars, const float* __restrict__ Vtab,
    const float* __restrict__ Kmat, const float* __restrict__ lstm_bias,
    const float* __restrict__ pred_W, const float* __restrict__ pred_b,
    const float* __restrict__ score_U, const float* __restrict__ bos,
    float* __restrict__ out, unsigned int* __restrict__ flags,
    float* __restrict__ nh_mb, float* __restrict__ pp_mb)
{
  const int blk = blockIdx.x;
  const int s = blk >> 5;     // 0..7  column-split index
  const int g = blk & 31;     // group (4 batch rows)
  const int tid = threadIdx.x;
  const int row0 = g * R_;

  __shared__ int   charsL[R_][T_];           // 4 KB
  __shared__ float ringVt[R_][4][L_ * DW_];  // 32 KB
  __shared__ float hring[4][R_][H_];         // 16 KB (full h, replicated)
  __shared__ float cring[4][R_][HC_];        // 2 KB (local chunk)
  __shared__ float pring[4][R_][DW_];        // 8 KB
  __shared__ float4 wordb4[L_][DW_];         // [w][e] -> 4 rows, 8 KB
  __shared__ float zxp[2][L_][R_][128];      // spec x-part partials (SoA), 16 KB
  __shared__ float sc8[8][R_][128];          // zh / pred partials (SoA), 16 KB
  __shared__ float4 xh4[H_];                 // h_prev per k, rows in components, 4 KB
  __shared__ float zc[R_][128];              // 2 KB
  __shared__ float nhf[R_][HC_];             // 512 B
  __shared__ float biasC[128];
  __shared__ float UL[DW_], pbL[DW_], bosL[DW_];
  __shared__ float scL[R_][L_];

  // ---- one-time loads ----
  if (tid < 128) biasC[tid] = lstm_bias[(tid >> 5) * H_ + s * HC_ + (tid & 31)];
  else if (tid < 256) UL[tid - 128] = score_U[tid - 128];
  else if (tid < 384) pbL[tid - 256] = pred_b[tid - 256];
  else if (tid < 512) bosL[tid - 384] = bos[tid - 384];
  for (int i = tid; i < R_ * T_; i += 1024)
    charsL[i >> 8][i & 255] = chars[(row0 + (i >> 8)) * T_ + (i & 255)];
  for (int i = tid; i < R_ * 4 * L_ * DW_; i += 1024) ((float*)ringVt)[i] = 0.0f;
  __syncthreads();

  // ---- bos step, fully local (x = bos, c0 = h0 = 0) ----
  {
    float a = lstm_bias[tid];
    #pragma unroll 8
    for (int k = 0; k < DC_; ++k) a = fmaf(bosL[k], Kmat[(size_t)k * Z4_ + tid], a);
    ((float*)sc8)[tid] = a;                     // zfull[col], 1024 floats
  }
  __syncthreads();
  if (tid < H_) {
    const float* zf_ = (const float*)sc8;
    float zi = zf_[tid], zj = zf_[H_ + tid], zo = zf_[3 * H_ + tid];
    float nc = sigm(zi) * tanhf(zj);
    float nh = tanhf(nc) * sigm(zo);
    #pragma unroll
    for (int q = 0; q < 4; ++q)
      #pragma unroll
      for (int r = 0; r < R_; ++r) hring[q][r][tid] = nh;
    int hl = tid - s * HC_;
    if (hl >= 0 && hl < HC_) {
      #pragma unroll
      for (int q = 0; q < 4; ++q)
        #pragma unroll
        for (int r = 0; r < R_; ++r) cring[q][r][hl] = nc;
    }
  }
  __syncthreads();
  { // pred0 = tanh(h1 @ pred_W + pred_b), full matvec (one-time)
    int kq = tid >> 7, e = tid & 127;
    float a = 0.0f;
    #pragma unroll 8
    for (int kk = kq * 32; kk < kq * 32 + 32; ++kk)
      a = fmaf(hring[0][0][kk], pred_W[(size_t)kk * DW_ + e], a);
    __syncthreads();                            // zfull fully consumed above
    ((float*)sc8)[tid] = a;
  }
  __syncthreads();
  if (tid < DW_) {
    float p = pbL[tid];
    #pragma unroll
    for (int kq = 0; kq < 8; ++kq) p += ((float*)sc8)[kq * 128 + tid];
    p = tanhf(p);
    #pragma unroll
    for (int q = 0; q < 4; ++q)
      #pragma unroll
      for (int r = 0; r < R_; ++r) pring[q][r][tid] = p;
  }
  __syncthreads();

  // ---- scan ----
  for (int t = 0; t < T_; ++t) {
    const int slot = t & 3;
    const int parW = t & 1;
    const int parR = (t - 1) & 1;

    // [1] Vtab gather for char t (independent of exchange)
    for (int i = tid; i < R_ * 512; i += 1024) {
      int r = i >> 9, idx = i & 511;
      ringVt[r][slot][idx] = Vtab[(size_t)charsL[r][t] * 512 + idx];
    }
    __syncthreads();
    // [2] word vectors, rows packed in float4
    if (tid < 512) {
      int w = tid >> 7, e = tid & 127;
      const float il = (w == 0) ? 1.0f : (w == 1) ? 0.5f : (w == 2) ? (1.0f / 3.0f) : 0.25f;
      float4 v;
      float* vp = (float*)&v;
      #pragma unroll
      for (int r = 0; r < R_; ++r) {
        float sa = 0.0f;
        #pragma unroll
        for (int c = 0; c < L_; ++c)
          if (c <= w) sa += ringVt[r][(t - c) & 3][w * DW_ + e];
        vp[r] = sa * il;
      }
      wordb4[w][e] = v;
    }
    __syncthreads();
    // [3] speculative x-part matvec for ALL 4 candidate windows
    {
      int kh = tid >> 9, w = (tid >> 7) & 3, c = tid & 127;
      int colg = (c >> 5) * H_ + s * HC_ + (c & 31);
      const float* Kp = Kmat + colg;
      float4 acc = make_float4(0.f, 0.f, 0.f, 0.f);
      #pragma unroll 8
      for (int k = kh * 64; k < kh * 64 + 64; ++k) {
        float wv = Kp[(size_t)k * Z4_];
        float4 x = wordb4[w][k];
        acc.x = fmaf(wv, x.x, acc.x);
        acc.y = fmaf(wv, x.y, acc.y);
        acc.z = fmaf(wv, x.z, acc.z);
        acc.w = fmaf(wv, x.w, acc.w);
      }
      zxp[kh][w][0][c] = acc.x; zxp[kh][w][1][c] = acc.y;
      zxp[kh][w][2][c] = acc.z; zxp[kh][w][3][c] = acc.w;
    }
    // [4] wait for partners' step t-1 (mostly already arrived), assemble
    if (t > 0 && tid < S_) {
      const unsigned tgt = (unsigned)t;
      const unsigned int* fp = &flags[tid * G_ + g];
      while (__hip_atomic_load(fp, __ATOMIC_RELAXED, __HIP_MEMORY_SCOPE_AGENT) < tgt)
        __builtin_amdgcn_s_sleep(2);
    }
    __syncthreads();
    if (t > 0) {
      {
        int r = tid >> 8, hh = tid & 255, sp = hh >> 5, hl = hh & 31;
        hring[(t - 1) & 3][r][hh] =
            ld_a(&nh_mb[(((size_t)parR * G_ + g) * S_ + sp) * (R_ * HC_) + r * HC_ + hl]);
      }
      if (tid < 512) {
        int r = tid >> 7, e = tid & 127;
        float acc = pbL[e];
        #pragma unroll
        for (int sp = 0; sp < S_; ++sp)
          acc += ld_a(&pp_mb[(((size_t)parR * G_ + g) * S_ + sp) * (R_ * DW_) + r * DW_ + e]);
        pring[(t - 1) & 3][r][e] = tanhf(acc);
      }
      __syncthreads();
    }
    // [5] scores: 16 waves, one per (r,w)
    {
      int wv = tid >> 6;
      int r = wv >> 2, w = wv & 3, l = tid & 63;
      int ps = (t - 1 - w) & 3;
      const float* wbF = (const float*)&wordb4[w][0];
      float pv = (pring[ps][r][l] + UL[l]) * wbF[(l << 2) | r]
               + (pring[ps][r][l + 64] + UL[l + 64]) * wbF[((l + 64) << 2) | r];
      #pragma unroll
      for (int off = 32; off; off >>= 1) pv += __shfl_down(pv, off);
      if (l == 0) scL[r][w] = (w <= t) ? pv : -1e30f;
    }
    __syncthreads();
    // [6] outputs (one block per group) + xh4 build; argmax recomputed inline
    if (s == 0 && tid < R_) {
      int bw = amax4(&scL[tid][0]);
      out[(row0 + tid) * T_ + t] = scL[tid][bw];
      out[B_ * T_ + (row0 + tid) * T_ + t] = (float)(bw + 1);
    }
    if (tid < H_) {
      float4 x;
      float* xp = (float*)&x;
      #pragma unroll
      for (int r = 0; r < R_; ++r) {
        int bw = amax4(&scL[r][0]);
        xp[r] = hring[(t - 1 - bw) & 3][r][tid];
      }
      xh4[tid] = x;
    }
    __syncthreads();
    // [7] h-part matvec
    {
      int kq = tid >> 7, c = tid & 127;
      int colg = (c >> 5) * H_ + s * HC_ + (c & 31);
      const float* Kp = Kmat + (size_t)DC_ * Z4_ + colg;
      float4 acc = make_float4(0.f, 0.f, 0.f, 0.f);
      #pragma unroll 8
      for (int k = kq * 32; k < kq * 32 + 32; ++k) {
        float wv = Kp[(size_t)k * Z4_];
        float4 x = xh4[k];
        acc.x = fmaf(wv, x.x, acc.x);
        acc.y = fmaf(wv, x.y, acc.y);
        acc.z = fmaf(wv, x.z, acc.z);
        acc.w = fmaf(wv, x.w, acc.w);
      }
      sc8[kq][0][c] = acc.x; sc8[kq][1][c] = acc.y;
      sc8[kq][2][c] = acc.z; sc8[kq][3][c] = acc.w;
    }
    __syncthreads();
    // [8] z reduce (pick speculative x-part for the chosen window)
    if (tid < 512) {
      int r = tid >> 7, c = tid & 127;
      int bw = amax4(&scL[r][0]);
      float z = biasC[c] + zxp[0][bw][r][c] + zxp[1][bw][r][c];
      #pragma unroll
      for (int kq = 0; kq < 8; ++kq) z += sc8[kq][r][c];
      zc[r][c] = z;
    }
    __syncthreads();
    // [9] gates -> nc, nh; publish nh chunk
    if (tid < R_ * HC_) {
      int r = tid >> 5, hl = tid & 31;
      int bw = amax4(&scL[r][0]);
      float zi = zc[r][hl], zj = zc[r][32 + hl], zf_ = zc[r][64 + hl], zo = zc[r][96 + hl];
      float cp = cring[(t - 1 - bw) & 3][r][hl];
      float nc = cp * sigm(zf_) + sigm(zi) * tanhf(zj);
      float nh = tanhf(nc) * sigm(zo);
      cring[slot][r][hl] = nc;
      nhf[r][hl] = nh;
      st_a(&nh_mb[(((size_t)parW * G_ + g) * S_ + s) * (R_ * HC_) + r * HC_ + hl], nh);
    }
    __syncthreads();
    // [10] pred partial over my 32 h-rows
    {
      int kk = tid >> 7, e = tid & 127;
      float4 acc = make_float4(0.f, 0.f, 0.f, 0.f);
      #pragma unroll
      for (int k2 = kk * 4; k2 < kk * 4 + 4; ++k2) {
        float wv = pred_W[(size_t)(s * HC_ + k2) * DW_ + e];
        acc.x = fmaf(wv, nhf[0][k2], acc.x);
        acc.y = fmaf(wv, nhf[1][k2], acc.y);
        acc.z = fmaf(wv, nhf[2][k2], acc.z);
        acc.w = fmaf(wv, nhf[3][k2], acc.w);
      }
      __syncthreads();          // sc8 (zh partials) consumed in [8]
      sc8[kk][0][e] = acc.x; sc8[kk][1][e] = acc.y;
      sc8[kk][2][e] = acc.z; sc8[kk][3][e] = acc.w;
    }
    __syncthreads();
    // [11] pp publish + flag
    if (tid < 512) {
      int r = tid >> 7, e = tid & 127;
      float a = 0.0f;
      #pragma unroll
      for (int kk = 0; kk < 8; ++kk) a += sc8[kk][r][e];
      st_a(&pp_mb[(((size_t)parW * G_ + g) * S_ + s) * (R_ * DW_) + r * DW_ + e], a);
    }
    __syncthreads();            // drains vmcnt before flag (barrier semantics)
    if (tid == 0)
      __hip_atomic_store(&flags[blk], (unsigned)(t + 1), __ATOMIC_RELEASE, __HIP_MEMORY_SCOPE_AGENT);
  }
}

extern "C" void kernel_launch(void* const* d_in, const int* in_sizes, int n_in,
                              void* d_out, int out_size, void* d_ws, size_t ws_size,
                              hipStream_t stream) {
  const int*   chars     = (const int*)d_in[0];
  const float* char_emb  = (const float*)d_in[1];
  const float* reset_W   = (const float*)d_in[2];
  const float* reset_b   = (const float*)d_in[3];
  const float* com_W     = (const float*)d_in[4];
  const float* com_b     = (const float*)d_in[5];
  const float* lstm_k    = (const float*)d_in[6];
  const float* lstm_bias = (const float*)d_in[7];
  const float* pred_W    = (const float*)d_in[8];
  const float* pred_b    = (const float*)d_in[9];
  const float* score_U   = (const float*)d_in[10];
  const float* bos       = (const float*)d_in[11];

  char* ws = (char*)d_ws;
  unsigned int* flags = (unsigned int*)(ws + WS_FLAGS);
  float* Vtab  = (float*)(ws + WS_VTAB);
  float* nh_mb = (float*)(ws + WS_NH);
  float* pp_mb = (float*)(ws + WS_PP);

  // d_ws is re-poisoned to 0xAA before every timed launch: flags MUST be zeroed.
  hipMemsetAsync(flags, 0, 256 * sizeof(unsigned int), stream);
  vtab_kernel<<<V_, 512, 0, stream>>>(char_emb, reset_W, reset_b, com_W, com_b, Vtab);
  seq_kernel<<<256, 1024, 0, stream>>>(chars, Vtab, lstm_k, lstm_bias, pred_W,
                                       pred_b, score_U, bos, (float*)d_out,
                                       flags, nh_mb, pp_mb);
}